// Round 2
// baseline (310.757 us; speedup 1.0000x reference)
//
#include <hip/hip_runtime.h>

// SSIM loss, fused separable 11x11 Gaussian over 5 fields (x, y, x^2, y^2, xy).
// R2: vectorized LDS (b128 everywhere), conflict-free strides, 3-stage finish.
//
// Per block: 32x32 output tile of one (n,c) plane.
//   P1: stage 42x42 x,y tiles in LDS (stride 44, zero halo)
//   P2: horizontal 11-tap conv -> 5 fields in hf (stride 36), float4 LDS IO
//   P3: 64 threads x (4 rows x 4 cols): vertical conv via float4 reads,
//       SSIM pointwise, block reduce -> partial[bid]
//   finishA: 48 blocks fold 256 partials each (in-place at partial[b*256])
//   finishB: 1 wave folds 48 -> out = 1 - mean

namespace {
constexpr int IMG  = 512;
constexpr int NCH  = 48;               // 16 * 3
constexpr int TS   = 32;
constexpr int HALO = 5;
constexpr int ITS  = TS + 2 * HALO;    // 42
constexpr int SSTR = 44;               // sx/sy row stride (16B-aligned cols)
constexpr int HSTR = 36;               // hf row stride (16B-aligned, non-pow2)
constexpr int TPR  = IMG / TS;         // 16
constexpr int NBLK = TPR * TPR * NCH;  // 12288
constexpr int FB   = NBLK / 256;       // 48
}

__global__ __launch_bounds__(256) void ssim_tile_kernel(
    const float* __restrict__ pred, const float* __restrict__ tgt,
    float* __restrict__ partial)
{
    constexpr float W[11] = {
        0.00102838f, 0.00759876f, 0.03600077f, 0.10936069f, 0.21300554f,
        0.26601172f,
        0.21300554f, 0.10936069f, 0.03600077f, 0.00759876f, 0.00102838f };

    __shared__ __align__(16) float sx[ITS][SSTR];   // 7.39 KB
    __shared__ __align__(16) float sy[ITS][SSTR];   // 7.39 KB
    __shared__ __align__(16) float hf[5][ITS][HSTR];// 30.24 KB
    __shared__ float wred[4];

    const int t    = threadIdx.x;
    const int bid  = blockIdx.x;
    const int img  = bid >> 8;
    const int tile = bid & 255;
    const int tx   = (tile & (TPR - 1)) * TS;
    const int ty   = (tile >> 4) * TS;

    const float* __restrict__ p = pred + (size_t)img * (IMG * IMG);
    const float* __restrict__ q = tgt  + (size_t)img * (IMG * IMG);

    // ---------------- P1: stage x,y with zero halo ----------------
    for (int l = t; l < ITS * ITS; l += 256) {
        int r  = l / ITS;
        int c  = l - r * ITS;
        int gy = ty + r - HALO;
        int gx = tx + c - HALO;
        float xv = 0.f, yv = 0.f;
        if (((unsigned)gy < (unsigned)IMG) && ((unsigned)gx < (unsigned)IMG)) {
            int gi = gy * IMG + gx;
            xv = p[gi];
            yv = q[gi];
        }
        sx[r][c] = xv;
        sy[r][c] = yv;
    }
    __syncthreads();

    // ------- P2: horizontal conv, 42 rows x 8 col-groups of 4 ----------
    for (int item = t; item < ITS * 8; item += 256) {
        int row = item >> 3;
        int c0  = (item & 7) << 2;
        // 4 float4 loads per array cover staged cols [c0, c0+15];
        // only [c0, c0+13] are used (tail elems may be garbage padding: unused).
        float4 bx[4], by[4];
        const float4* px = (const float4*)&sx[row][c0];
        const float4* py = (const float4*)&sy[row][c0];
        #pragma unroll
        for (int u = 0; u < 4; ++u) { bx[u] = px[u]; by[u] = py[u]; }
        const float* fx = (const float*)bx;
        const float* fy = (const float*)by;

        float a0[4] = {}, a1[4] = {}, a2[4] = {}, a3[4] = {}, a4[4] = {};
        #pragma unroll
        for (int i = 0; i < 14; ++i) {
            float xv = fx[i], yv = fy[i];
            float xx = xv * xv, yy = yv * yv, xy = xv * yv;
            #pragma unroll
            for (int j = 0; j < 4; ++j) {
                int k = i - j;
                if (k >= 0 && k < 11) {
                    float w = W[k];
                    a0[j] += w * xv; a1[j] += w * yv;
                    a2[j] += w * xx; a3[j] += w * yy; a4[j] += w * xy;
                }
            }
        }
        *(float4*)&hf[0][row][c0] = make_float4(a0[0], a0[1], a0[2], a0[3]);
        *(float4*)&hf[1][row][c0] = make_float4(a1[0], a1[1], a1[2], a1[3]);
        *(float4*)&hf[2][row][c0] = make_float4(a2[0], a2[1], a2[2], a2[3]);
        *(float4*)&hf[3][row][c0] = make_float4(a3[0], a3[1], a3[2], a3[3]);
        *(float4*)&hf[4][row][c0] = make_float4(a4[0], a4[1], a4[2], a4[3]);
    }
    __syncthreads();

    // ------- P3: 64 threads, each 4 rows x 4 cols, float4 column march ------
    float lsum = 0.f;
    if (t < 64) {
        const int c0 = (t & 7) << 2;
        const int r0 = (t >> 3) << 2;
        float4 acc[5][4];
        #pragma unroll
        for (int f = 0; f < 5; ++f)
            #pragma unroll
            for (int j = 0; j < 4; ++j)
                acc[f][j] = make_float4(0.f, 0.f, 0.f, 0.f);

        #pragma unroll
        for (int i = 0; i < 14; ++i) {
            float4 v[5];
            #pragma unroll
            for (int f = 0; f < 5; ++f)
                v[f] = *(const float4*)&hf[f][r0 + i][c0];
            #pragma unroll
            for (int j = 0; j < 4; ++j) {
                int k = i - j;
                if (k >= 0 && k < 11) {
                    float w = W[k];
                    #pragma unroll
                    for (int f = 0; f < 5; ++f) {
                        acc[f][j].x += w * v[f].x;
                        acc[f][j].y += w * v[f].y;
                        acc[f][j].z += w * v[f].z;
                        acc[f][j].w += w * v[f].w;
                    }
                }
            }
        }

        constexpr float C1 = 1e-4f, C2 = 9e-4f;
        const float* af = (const float*)acc;   // [f][j][comp] fully unrolled
        #pragma unroll
        for (int j = 0; j < 4; ++j) {
            #pragma unroll
            for (int cm = 0; cm < 4; ++cm) {
                int o = j * 4 + cm;
                float mx  = af[ 0 + o];
                float my  = af[16 + o];
                float ex2 = af[32 + o];
                float ey2 = af[48 + o];
                float exy = af[64 + o];
                float mxs = mx * mx, mys = my * my, mxy = mx * my;
                float sgx  = ex2 - mxs;
                float sgy  = ey2 - mys;
                float sgxy = exy - mxy;
                float num = (2.f * mxy + C1) * (2.f * sgxy + C2);
                float den = (mxs + mys + C1) * (sgx + sgy + C2);
                lsum += num / den;
            }
        }
    }

    #pragma unroll
    for (int off = 32; off > 0; off >>= 1)
        lsum += __shfl_down(lsum, off, 64);
    if ((t & 63) == 0) wred[t >> 6] = lsum;
    __syncthreads();
    if (t == 0) partial[bid] = wred[0] + wred[1] + wred[2] + wred[3];
}

__global__ __launch_bounds__(256) void ssim_finishA(float* __restrict__ partial)
{
    __shared__ float wred[4];
    const int t = threadIdx.x;
    float s = partial[blockIdx.x * 256 + t];
    #pragma unroll
    for (int off = 32; off > 0; off >>= 1)
        s += __shfl_down(s, off, 64);
    if ((t & 63) == 0) wred[t >> 6] = s;
    __syncthreads();
    // write into own read-range head: no cross-block hazard
    if (t == 0) partial[blockIdx.x * 256] = wred[0] + wred[1] + wred[2] + wred[3];
}

__global__ __launch_bounds__(64) void ssim_finishB(
    const float* __restrict__ partial, float* __restrict__ out)
{
    const int t = threadIdx.x;
    float s = (t < FB) ? partial[t * 256] : 0.f;
    #pragma unroll
    for (int off = 32; off > 0; off >>= 1)
        s += __shfl_down(s, off, 64);
    if (t == 0)
        out[0] = 1.f - s * (1.f / (float)((long long)NCH * IMG * IMG));
}

extern "C" void kernel_launch(void* const* d_in, const int* in_sizes, int n_in,
                              void* d_out, int out_size, void* d_ws, size_t ws_size,
                              hipStream_t stream)
{
    const float* pred = (const float*)d_in[0];
    const float* tgt  = (const float*)d_in[1];
    float* out     = (float*)d_out;
    float* partial = (float*)d_ws;    // NBLK floats = 48 KB

    ssim_tile_kernel<<<NBLK, 256, 0, stream>>>(pred, tgt, partial);
    ssim_finishA<<<FB, 256, 0, stream>>>(partial);
    ssim_finishB<<<1, 64, 0, stream>>>(partial, out);
}

// Round 3
// 208.301 us; speedup vs baseline: 1.4919x; 1.4919x over previous
//
#include <hip/hip_runtime.h>

// SSIM loss, fused separable 11x11 Gaussian over 5 fields (x, y, x^2, y^2, xy).
// R3: no input LDS staging (global->reg h-conv, L1 serves halo overlap),
//     32x64 tile, all-b32 LDS with conflict-free strides, 8-row register
//     blocking in the vertical pass, rcp instead of exact div.
//
// Per block: 32 cols x 64 rows of one (n,c) plane.
//   P2: horizontal 11-tap conv, inputs direct from global (aligned float4),
//       -> hf[5][74][33] in LDS (b32 stores, <=2-way banks)
//   P3: vertical 11-tap conv: thread = (col, 8-row group); 90 b32 reads
//       (one shared vaddr + imm offsets) -> 8 SSIM values -> block reduce
//   finishA: 24 blocks fold 256 partials; finishB: 1 wave folds 24.

namespace {
constexpr int IMG   = 512;
constexpr int NCH   = 48;              // 16 * 3
constexpr int TW    = 32;              // tile cols
constexpr int TH    = 64;              // tile rows
constexpr int HALO  = 5;
constexpr int HROWS = TH + 2 * HALO;   // 74
constexpr int HSTR  = 33;              // hf col stride (odd)
constexpr int TPX   = IMG / TW;        // 16
constexpr int TPY   = IMG / TH;        // 8
constexpr int NBLK  = TPX * TPY * NCH; // 6144
constexpr int FB    = NBLK / 256;      // 24
}

__global__ __launch_bounds__(256) void ssim_tile_kernel(
    const float* __restrict__ pred, const float* __restrict__ tgt,
    float* __restrict__ partial)
{
    constexpr float W[11] = {
        0.00102838f, 0.00759876f, 0.03600077f, 0.10936069f, 0.21300554f,
        0.26601172f,
        0.21300554f, 0.10936069f, 0.03600077f, 0.00759876f, 0.00102838f };

    __shared__ float hf[5][HROWS][HSTR];   // 48.84 KB
    __shared__ float wred[4];

    const int t    = threadIdx.x;
    const int bid  = blockIdx.x;
    const int img  = bid >> 7;             // 128 tiles per plane
    const int tile = bid & 127;
    const int tx   = (tile & 15) * TW;
    const int ty   = (tile >> 4) * TH;

    const float* __restrict__ p = pred + (size_t)img * (IMG * IMG);
    const float* __restrict__ q = tgt  + (size_t)img * (IMG * IMG);

    // ---- P2: horizontal conv, 74 rows x 8 col-groups of 4, global -> LDS ----
    for (int item = t; item < HROWS * 8; item += 256) {
        const int row  = item >> 3;            // 0..73
        const int g    = item & 7;
        const int gy   = ty + row - HALO;
        const int col4 = tx + (g << 2);        // multiple of 4
        const bool row_ok = (unsigned)gy < (unsigned)IMG;
        const float* rp = p + gy * IMG;
        const float* rq = q + gy * IMG;

        float xin[14], yin[14];
        if (row_ok && col4 >= 8 && col4 <= 500) {
            // cols col4-5 .. col4+8; (col4-4) is 16B aligned
            xin[0] = rp[col4 - 5];
            *(float4*)&xin[1] = *(const float4*)(rp + col4 - 4);
            *(float4*)&xin[5] = *(const float4*)(rp + col4);
            *(float4*)&xin[9] = *(const float4*)(rp + col4 + 4);
            xin[13] = rp[col4 + 8];
            yin[0] = rq[col4 - 5];
            *(float4*)&yin[1] = *(const float4*)(rq + col4 - 4);
            *(float4*)&yin[5] = *(const float4*)(rq + col4);
            *(float4*)&yin[9] = *(const float4*)(rq + col4 + 4);
            yin[13] = rq[col4 + 8];
        } else {
            #pragma unroll
            for (int i = 0; i < 14; ++i) {
                int gx = col4 - 5 + i;
                bool ok = row_ok && ((unsigned)gx < (unsigned)IMG);
                xin[i] = ok ? rp[gx] : 0.f;
                yin[i] = ok ? rq[gx] : 0.f;
            }
        }

        float a0[4] = {}, a1[4] = {}, a2[4] = {}, a3[4] = {}, a4[4] = {};
        #pragma unroll
        for (int i = 0; i < 14; ++i) {
            float xv = xin[i], yv = yin[i];
            float xx = xv * xv, yy = yv * yv, xy = xv * yv;
            #pragma unroll
            for (int j = 0; j < 4; ++j) {
                int k = i - j;
                if (k >= 0 && k < 11) {
                    float w = W[k];
                    a0[j] += w * xv; a1[j] += w * yv;
                    a2[j] += w * xx; a3[j] += w * yy; a4[j] += w * xy;
                }
            }
        }
        const int lc = g << 2;
        #pragma unroll
        for (int j = 0; j < 4; ++j) {
            hf[0][row][lc + j] = a0[j];
            hf[1][row][lc + j] = a1[j];
            hf[2][row][lc + j] = a2[j];
            hf[3][row][lc + j] = a3[j];
            hf[4][row][lc + j] = a4[j];
        }
    }
    __syncthreads();

    // ---- P3: vertical conv; thread = (col c, rows r0..r0+7) ----
    const int c  = t & 31;
    const int r0 = (t >> 5) << 3;
    float b0[8] = {}, b1[8] = {}, b2[8] = {}, b3[8] = {}, b4[8] = {};
    #pragma unroll
    for (int i = 0; i < 18; ++i) {
        float v0 = hf[0][r0 + i][c];
        float v1 = hf[1][r0 + i][c];
        float v2 = hf[2][r0 + i][c];
        float v3 = hf[3][r0 + i][c];
        float v4 = hf[4][r0 + i][c];
        #pragma unroll
        for (int j = 0; j < 8; ++j) {
            int k = i - j;
            if (k >= 0 && k < 11) {
                float w = W[k];
                b0[j] += w * v0; b1[j] += w * v1; b2[j] += w * v2;
                b3[j] += w * v3; b4[j] += w * v4;
            }
        }
    }

    constexpr float C1 = 1e-4f, C2 = 9e-4f;
    float lsum = 0.f;
    #pragma unroll
    for (int j = 0; j < 8; ++j) {
        float mx  = b0[j], my = b1[j];
        float mxs = mx * mx, mys = my * my, mxy = mx * my;
        float sgx  = b2[j] - mxs;
        float sgy  = b3[j] - mys;
        float sgxy = b4[j] - mxy;
        float num = (2.f * mxy + C1) * (2.f * sgxy + C2);
        float den = (mxs + mys + C1) * (sgx + sgy + C2);
        lsum += num * __builtin_amdgcn_rcpf(den);
    }

    #pragma unroll
    for (int off = 32; off > 0; off >>= 1)
        lsum += __shfl_down(lsum, off, 64);
    if ((t & 63) == 0) wred[t >> 6] = lsum;
    __syncthreads();
    if (t == 0) partial[bid] = wred[0] + wred[1] + wred[2] + wred[3];
}

__global__ __launch_bounds__(256) void ssim_finishA(float* __restrict__ partial)
{
    __shared__ float wred[4];
    const int t = threadIdx.x;
    float s = partial[blockIdx.x * 256 + t];
    #pragma unroll
    for (int off = 32; off > 0; off >>= 1)
        s += __shfl_down(s, off, 64);
    if ((t & 63) == 0) wred[t >> 6] = s;
    __syncthreads();
    if (t == 0) partial[blockIdx.x * 256] = wred[0] + wred[1] + wred[2] + wred[3];
}

__global__ __launch_bounds__(64) void ssim_finishB(
    const float* __restrict__ partial, float* __restrict__ out)
{
    const int t = threadIdx.x;
    float s = (t < FB) ? partial[t * 256] : 0.f;
    #pragma unroll
    for (int off = 32; off > 0; off >>= 1)
        s += __shfl_down(s, off, 64);
    if (t == 0)
        out[0] = 1.f - s * (1.f / (float)((long long)NCH * IMG * IMG));
}

extern "C" void kernel_launch(void* const* d_in, const int* in_sizes, int n_in,
                              void* d_out, int out_size, void* d_ws, size_t ws_size,
                              hipStream_t stream)
{
    const float* pred = (const float*)d_in[0];
    const float* tgt  = (const float*)d_in[1];
    float* out     = (float*)d_out;
    float* partial = (float*)d_ws;    // NBLK floats = 24 KB

    ssim_tile_kernel<<<NBLK, 256, 0, stream>>>(pred, tgt, partial);
    ssim_finishA<<<FB, 256, 0, stream>>>(partial);
    ssim_finishB<<<1, 64, 0, stream>>>(partial, out);
}

// Round 4
// 186.485 us; speedup vs baseline: 1.6664x; 1.1170x over previous
//
#include <hip/hip_runtime.h>
#include <hip/hip_fp16.h>

// SSIM loss, fused separable 11x11 Gaussian over 5 fields (x, y, x^2, y^2, xy).
// R4: fp16 half2 intermediate in LDS (26.6 KB -> 6 blocks/CU, was 3),
//     P3 reads col-pairs as half2 (70 reads / 8 outputs), conv math fp32.
//
// Per block: 32 cols x 64 rows of one (n,c) plane.
//   P2: horizontal 11-tap conv from global (aligned float4) -> hf[5][74][18]
//       as half2 col-pairs (10 stores/item).
//   P3: vertical 11-tap conv: thread = (col-pair p, 4-row group g);
//       70 half2 reads -> 8 SSIM values (fp32 math) -> block reduce.
//   finishA: 24 blocks fold 256 partials; finishB: 1 wave folds 24.

namespace {
constexpr int IMG   = 512;
constexpr int NCH   = 48;              // 16 * 3
constexpr int TW    = 32;              // tile cols
constexpr int TH    = 64;              // tile rows
constexpr int HALO  = 5;
constexpr int HROWS = TH + 2 * HALO;   // 74
constexpr int PSTR  = 18;              // hf stride in half2 units (16 pairs + 2)
constexpr int TPX   = IMG / TW;        // 16
constexpr int TPY   = IMG / TH;        // 8
constexpr int NBLK  = TPX * TPY * NCH; // 6144
constexpr int FB    = NBLK / 256;      // 24
}

__global__ __launch_bounds__(256) void ssim_tile_kernel(
    const float* __restrict__ pred, const float* __restrict__ tgt,
    float* __restrict__ partial)
{
    constexpr float W[11] = {
        0.00102838f, 0.00759876f, 0.03600077f, 0.10936069f, 0.21300554f,
        0.26601172f,
        0.21300554f, 0.10936069f, 0.03600077f, 0.00759876f, 0.00102838f };

    __shared__ __half2 hf[5][HROWS][PSTR];   // 26.64 KB
    __shared__ float wred[4];

    const int t    = threadIdx.x;
    const int bid  = blockIdx.x;
    const int img  = bid >> 7;             // 128 tiles per plane
    const int tile = bid & 127;
    const int tx   = (tile & 15) * TW;
    const int ty   = (tile >> 4) * TH;

    const float* __restrict__ p = pred + (size_t)img * (IMG * IMG);
    const float* __restrict__ q = tgt  + (size_t)img * (IMG * IMG);

    // ---- P2: horizontal conv, 74 rows x 8 col-groups of 4, global -> LDS ----
    for (int item = t; item < HROWS * 8; item += 256) {
        const int row  = item >> 3;            // 0..73
        const int g    = item & 7;
        const int gy   = ty + row - HALO;
        const int col4 = tx + (g << 2);        // multiple of 4
        const bool row_ok = (unsigned)gy < (unsigned)IMG;
        const float* rp = p + gy * IMG;
        const float* rq = q + gy * IMG;

        float xin[14], yin[14];
        if (row_ok && col4 >= 8 && col4 <= 500) {
            // cols col4-5 .. col4+8; (col4-4) is 16B aligned
            xin[0] = rp[col4 - 5];
            *(float4*)&xin[1] = *(const float4*)(rp + col4 - 4);
            *(float4*)&xin[5] = *(const float4*)(rp + col4);
            *(float4*)&xin[9] = *(const float4*)(rp + col4 + 4);
            xin[13] = rp[col4 + 8];
            yin[0] = rq[col4 - 5];
            *(float4*)&yin[1] = *(const float4*)(rq + col4 - 4);
            *(float4*)&yin[5] = *(const float4*)(rq + col4);
            *(float4*)&yin[9] = *(const float4*)(rq + col4 + 4);
            yin[13] = rq[col4 + 8];
        } else {
            #pragma unroll
            for (int i = 0; i < 14; ++i) {
                int gx = col4 - 5 + i;
                bool ok = row_ok && ((unsigned)gx < (unsigned)IMG);
                xin[i] = ok ? rp[gx] : 0.f;
                yin[i] = ok ? rq[gx] : 0.f;
            }
        }

        float a0[4] = {}, a1[4] = {}, a2[4] = {}, a3[4] = {}, a4[4] = {};
        #pragma unroll
        for (int i = 0; i < 14; ++i) {
            float xv = xin[i], yv = yin[i];
            float xx = xv * xv, yy = yv * yv, xy = xv * yv;
            #pragma unroll
            for (int j = 0; j < 4; ++j) {
                int k = i - j;
                if (k >= 0 && k < 11) {
                    float w = W[k];
                    a0[j] += w * xv; a1[j] += w * yv;
                    a2[j] += w * xx; a3[j] += w * yy; a4[j] += w * xy;
                }
            }
        }
        const int pc = g << 1;   // half2 pair index base
        hf[0][row][pc]     = __float22half2_rn(make_float2(a0[0], a0[1]));
        hf[0][row][pc + 1] = __float22half2_rn(make_float2(a0[2], a0[3]));
        hf[1][row][pc]     = __float22half2_rn(make_float2(a1[0], a1[1]));
        hf[1][row][pc + 1] = __float22half2_rn(make_float2(a1[2], a1[3]));
        hf[2][row][pc]     = __float22half2_rn(make_float2(a2[0], a2[1]));
        hf[2][row][pc + 1] = __float22half2_rn(make_float2(a2[2], a2[3]));
        hf[3][row][pc]     = __float22half2_rn(make_float2(a3[0], a3[1]));
        hf[3][row][pc + 1] = __float22half2_rn(make_float2(a3[2], a3[3]));
        hf[4][row][pc]     = __float22half2_rn(make_float2(a4[0], a4[1]));
        hf[4][row][pc + 1] = __float22half2_rn(make_float2(a4[2], a4[3]));
    }
    __syncthreads();

    // ---- P3: vertical conv; thread = (col-pair p, 4-row group g) ----
    const int pr = t & 15;          // col pair 0..15
    const int r0 = (t >> 4) << 2;   // row group base, 0..60
    float2 b0[4] = {}, b1[4] = {}, b2[4] = {}, b3[4] = {}, b4[4] = {};
    #pragma unroll
    for (int i = 0; i < 14; ++i) {
        float2 v0 = __half22float2(hf[0][r0 + i][pr]);
        float2 v1 = __half22float2(hf[1][r0 + i][pr]);
        float2 v2 = __half22float2(hf[2][r0 + i][pr]);
        float2 v3 = __half22float2(hf[3][r0 + i][pr]);
        float2 v4 = __half22float2(hf[4][r0 + i][pr]);
        #pragma unroll
        for (int j = 0; j < 4; ++j) {
            int k = i - j;
            if (k >= 0 && k < 11) {
                float w = W[k];
                b0[j].x += w * v0.x; b0[j].y += w * v0.y;
                b1[j].x += w * v1.x; b1[j].y += w * v1.y;
                b2[j].x += w * v2.x; b2[j].y += w * v2.y;
                b3[j].x += w * v3.x; b3[j].y += w * v3.y;
                b4[j].x += w * v4.x; b4[j].y += w * v4.y;
            }
        }
    }

    constexpr float C1 = 1e-4f, C2 = 9e-4f;
    float lsum = 0.f;
    #pragma unroll
    for (int j = 0; j < 4; ++j) {
        #pragma unroll
        for (int h = 0; h < 2; ++h) {
            float mx  = h ? b0[j].y : b0[j].x;
            float my  = h ? b1[j].y : b1[j].x;
            float ex2 = h ? b2[j].y : b2[j].x;
            float ey2 = h ? b3[j].y : b3[j].x;
            float exy = h ? b4[j].y : b4[j].x;
            float mxs = mx * mx, mys = my * my, mxy = mx * my;
            float sgx  = ex2 - mxs;
            float sgy  = ey2 - mys;
            float sgxy = exy - mxy;
            float num = (2.f * mxy + C1) * (2.f * sgxy + C2);
            float den = (mxs + mys + C1) * (sgx + sgy + C2);
            lsum += num * __builtin_amdgcn_rcpf(den);
        }
    }

    #pragma unroll
    for (int off = 32; off > 0; off >>= 1)
        lsum += __shfl_down(lsum, off, 64);
    if ((t & 63) == 0) wred[t >> 6] = lsum;
    __syncthreads();
    if (t == 0) partial[bid] = wred[0] + wred[1] + wred[2] + wred[3];
}

__global__ __launch_bounds__(256) void ssim_finishA(float* __restrict__ partial)
{
    __shared__ float wred[4];
    const int t = threadIdx.x;
    float s = partial[blockIdx.x * 256 + t];
    #pragma unroll
    for (int off = 32; off > 0; off >>= 1)
        s += __shfl_down(s, off, 64);
    if ((t & 63) == 0) wred[t >> 6] = s;
    __syncthreads();
    if (t == 0) partial[blockIdx.x * 256] = wred[0] + wred[1] + wred[2] + wred[3];
}

__global__ __launch_bounds__(64) void ssim_finishB(
    const float* __restrict__ partial, float* __restrict__ out)
{
    const int t = threadIdx.x;
    float s = (t < FB) ? partial[t * 256] : 0.f;
    #pragma unroll
    for (int off = 32; off > 0; off >>= 1)
        s += __shfl_down(s, off, 64);
    if (t == 0)
        out[0] = 1.f - s * (1.f / (float)((long long)NCH * IMG * IMG));
}

extern "C" void kernel_launch(void* const* d_in, const int* in_sizes, int n_in,
                              void* d_out, int out_size, void* d_ws, size_t ws_size,
                              hipStream_t stream)
{
    const float* pred = (const float*)d_in[0];
    const float* tgt  = (const float*)d_in[1];
    float* out     = (float*)d_out;
    float* partial = (float*)d_ws;    // NBLK floats = 24 KB

    ssim_tile_kernel<<<NBLK, 256, 0, stream>>>(pred, tgt, partial);
    ssim_finishA<<<FB, 256, 0, stream>>>(partial);
    ssim_finishB<<<1, 64, 0, stream>>>(partial, out);
}

// Round 5
// 172.410 us; speedup vs baseline: 1.8024x; 1.0816x over previous
//
#include <hip/hip_runtime.h>
#include <hip/hip_fp16.h>

// SSIM loss, fused separable 11x11 Gaussian over 5 fields (x, y, x^2, y^2, xy).
// R5: packed-fp16 conv math (v_pk_fma_f16 = 2 MACs/instr) in both passes.
//   Field packing: hf_ab = (x,y) half2, hf_cd = (x2,y2) half2, hf_e = xy half.
//   P2: global float4 -> fp16 pack -> h-conv (110 pk_fma/item) -> 3 LDS stores
//       (b128 ab, b128 cd, b64 e).
//   P3: thread = (col, 8-row group): 54 LDS reads, 220 pk_fma, fp32 SSIM.
//   finishA: 24 blocks fold 256 partials; finishB: 1 wave folds 24.

namespace {
constexpr int IMG   = 512;
constexpr int NCH   = 48;              // 16 * 3
constexpr int TW    = 32;              // tile cols
constexpr int TH    = 64;              // tile rows
constexpr int HALO  = 5;
constexpr int HROWS = TH + 2 * HALO;   // 74
constexpr int ABSTR = 36;              // hf_ab/cd stride (half2 units)
constexpr int ESTR  = 36;              // hf_e stride (half units)
constexpr int TPX   = IMG / TW;        // 16
constexpr int TPY   = IMG / TH;        // 8
constexpr int NBLK  = TPX * TPY * NCH; // 6144
constexpr int FB    = NBLK / 256;      // 24
}

__global__ __launch_bounds__(256, 6) void ssim_tile_kernel(
    const float* __restrict__ pred, const float* __restrict__ tgt,
    float* __restrict__ partial)
{
    constexpr float Wf[11] = {
        0.00102838f, 0.00759876f, 0.03600077f, 0.10936069f, 0.21300554f,
        0.26601172f,
        0.21300554f, 0.10936069f, 0.03600077f, 0.00759876f, 0.00102838f };

    // broadcast weights and (W[d], W[d-1]) pair table (folds to constants)
    __half2 W2[11], WP[12];
    #pragma unroll
    for (int k = 0; k < 11; ++k) W2[k] = __float2half2_rn(Wf[k]);
    #pragma unroll
    for (int d = 0; d < 12; ++d) {
        float lo = (d <= 10) ? Wf[d] : 0.f;
        float hi = (d >= 1) ? Wf[d - 1] : 0.f;
        WP[d] = __floats2half2_rn(lo, hi);
    }

    __shared__ __align__(16) __half2 hf_ab[HROWS][ABSTR];  // 10.41 KB
    __shared__ __align__(16) __half2 hf_cd[HROWS][ABSTR];  // 10.41 KB
    __shared__ __align__(16) __half  hf_e [HROWS][ESTR];   //  5.20 KB
    __shared__ float wred[4];

    const int t    = threadIdx.x;
    const int bid  = blockIdx.x;
    const int img  = bid >> 7;             // 128 tiles per plane
    const int tile = bid & 127;
    const int tx   = (tile & 15) * TW;
    const int ty   = (tile >> 4) * TH;

    const float* __restrict__ p = pred + (size_t)img * (IMG * IMG);
    const float* __restrict__ q = tgt  + (size_t)img * (IMG * IMG);

    // ---- P2: horizontal conv, 74 rows x 8 col-groups of 4, global -> LDS ----
    for (int item = t; item < HROWS * 8; item += 256) {
        const int row  = item >> 3;            // 0..73
        const int g    = item & 7;
        const int gy   = ty + row - HALO;
        const int col4 = tx + (g << 2);        // multiple of 4
        const bool row_ok = (unsigned)gy < (unsigned)IMG;
        const float* rp = p + gy * IMG;
        const float* rq = q + gy * IMG;

        float xin[14], yin[14];
        if (row_ok && col4 >= 8 && col4 <= 500) {
            xin[0] = rp[col4 - 5];
            *(float4*)&xin[1] = *(const float4*)(rp + col4 - 4);
            *(float4*)&xin[5] = *(const float4*)(rp + col4);
            *(float4*)&xin[9] = *(const float4*)(rp + col4 + 4);
            xin[13] = rp[col4 + 8];
            yin[0] = rq[col4 - 5];
            *(float4*)&yin[1] = *(const float4*)(rq + col4 - 4);
            *(float4*)&yin[5] = *(const float4*)(rq + col4);
            *(float4*)&yin[9] = *(const float4*)(rq + col4 + 4);
            yin[13] = rq[col4 + 8];
        } else {
            #pragma unroll
            for (int i = 0; i < 14; ++i) {
                int gx = col4 - 5 + i;
                bool ok = row_ok && ((unsigned)gx < (unsigned)IMG);
                xin[i] = ok ? rp[gx] : 0.f;
                yin[i] = ok ? rq[gx] : 0.f;
            }
        }

        __half2 z = __float2half2_rn(0.f);
        __align__(16) __half2 aab[4] = {z, z, z, z};
        __align__(16) __half2 acd[4] = {z, z, z, z};
        __align__(8)  __half2 ae[2]  = {z, z};
        #pragma unroll
        for (int i = 0; i < 14; ++i) {
            __half2 hxy = __floats2half2_rn(xin[i], yin[i]);       // (x, y)
            __half2 hsq = __hmul2(hxy, hxy);                       // (x2, y2)
            __half2 hxe = __hmul2(hxy, __lowhigh2highlow(hxy));    // (xy, xy)
            #pragma unroll
            for (int j = 0; j < 4; ++j) {
                int k = i - j;
                if (k >= 0 && k < 11) {
                    aab[j] = __hfma2(W2[k], hxy, aab[j]);
                    acd[j] = __hfma2(W2[k], hsq, acd[j]);
                }
            }
            #pragma unroll
            for (int pp = 0; pp < 2; ++pp) {     // output col pairs (2pp, 2pp+1)
                int d = i - 2 * pp;
                if (d >= 0 && d < 12) ae[pp] = __hfma2(WP[d], hxe, ae[pp]);
            }
        }
        const int lc = g << 2;
        *(float4*)&hf_ab[row][lc] = *(const float4*)aab;   // 4 half2 = 16 B
        *(float4*)&hf_cd[row][lc] = *(const float4*)acd;
        *(float2*)&hf_e [row][lc] = *(const float2*)ae;    // 4 half = 8 B
    }
    __syncthreads();

    // ---- P3: vertical conv; thread = (col c, 8-row group) ----
    const int c  = t & 31;
    const int r0 = (t >> 5) << 3;          // 0..56
    __half2 z = __float2half2_rn(0.f);
    __half2 bab[8] = {z,z,z,z,z,z,z,z};
    __half2 bcd[8] = {z,z,z,z,z,z,z,z};
    __half2 be[4]  = {z,z,z,z};
    #pragma unroll
    for (int i = 0; i < 18; ++i) {
        __half2 vab = hf_ab[r0 + i][c];
        __half2 vcd = hf_cd[r0 + i][c];
        __half2 ve2 = __half2half2(hf_e[r0 + i][c]);
        #pragma unroll
        for (int j = 0; j < 8; ++j) {
            int k = i - j;
            if (k >= 0 && k < 11) {
                bab[j] = __hfma2(W2[k], vab, bab[j]);
                bcd[j] = __hfma2(W2[k], vcd, bcd[j]);
            }
        }
        #pragma unroll
        for (int qq = 0; qq < 4; ++qq) {   // output row pairs (2qq, 2qq+1)
            int d = i - 2 * qq;
            if (d >= 0 && d < 12) be[qq] = __hfma2(WP[d], ve2, be[qq]);
        }
    }

    constexpr float C1 = 1e-4f, C2 = 9e-4f;
    float lsum = 0.f;
    #pragma unroll
    for (int j = 0; j < 8; ++j) {
        float2 ab = __half22float2(bab[j]);
        float2 cd = __half22float2(bcd[j]);
        float exy = __half2float((j & 1) ? __high2half(be[j >> 1])
                                         : __low2half(be[j >> 1]));
        float mx = ab.x, my = ab.y;
        float mxs = mx * mx, mys = my * my, mxy = mx * my;
        float sgx  = cd.x - mxs;
        float sgy  = cd.y - mys;
        float sgxy = exy  - mxy;
        float num = (2.f * mxy + C1) * (2.f * sgxy + C2);
        float den = (mxs + mys + C1) * (sgx + sgy + C2);
        lsum += num * __builtin_amdgcn_rcpf(den);
    }

    #pragma unroll
    for (int off = 32; off > 0; off >>= 1)
        lsum += __shfl_down(lsum, off, 64);
    if ((t & 63) == 0) wred[t >> 6] = lsum;
    __syncthreads();
    if (t == 0) partial[bid] = wred[0] + wred[1] + wred[2] + wred[3];
}

__global__ __launch_bounds__(256) void ssim_finishA(float* __restrict__ partial)
{
    __shared__ float wred[4];
    const int t = threadIdx.x;
    float s = partial[blockIdx.x * 256 + t];
    #pragma unroll
    for (int off = 32; off > 0; off >>= 1)
        s += __shfl_down(s, off, 64);
    if ((t & 63) == 0) wred[t >> 6] = s;
    __syncthreads();
    if (t == 0) partial[blockIdx.x * 256] = wred[0] + wred[1] + wred[2] + wred[3];
}

__global__ __launch_bounds__(64) void ssim_finishB(
    const float* __restrict__ partial, float* __restrict__ out)
{
    const int t = threadIdx.x;
    float s = (t < FB) ? partial[t * 256] : 0.f;
    #pragma unroll
    for (int off = 32; off > 0; off >>= 1)
        s += __shfl_down(s, off, 64);
    if (t == 0)
        out[0] = 1.f - s * (1.f / (float)((long long)NCH * IMG * IMG));
}

extern "C" void kernel_launch(void* const* d_in, const int* in_sizes, int n_in,
                              void* d_out, int out_size, void* d_ws, size_t ws_size,
                              hipStream_t stream)
{
    const float* pred = (const float*)d_in[0];
    const float* tgt  = (const float*)d_in[1];
    float* out     = (float*)d_out;
    float* partial = (float*)d_ws;    // NBLK floats = 24 KB

    ssim_tile_kernel<<<NBLK, 256, 0, stream>>>(pred, tgt, partial);
    ssim_finishA<<<FB, 256, 0, stream>>>(partial);
    ssim_finishB<<<1, 64, 0, stream>>>(partial, out);
}

// Round 6
// 142.368 us; speedup vs baseline: 2.1828x; 1.2110x over previous
//
#include <hip/hip_runtime.h>
#include <hip/hip_fp16.h>

// SSIM loss, fused separable 11x11 Gaussian over 5 fields (x, y, x^2, y^2, xy).
// R6: RTZ packed cvt (1 instr/pair), 8-col P2 items, block-uniform edge path,
//     ab/cd interleaved in LDS (P3 reads b64), XCD-aware tile swizzle.
//   hf_abcd[row][col] = {(x,y)conv, (x2,y2)conv} half2 pair (b64/lane reads)
//   hf_e[row][col]    = (xy)conv half
//   finishA: 24 blocks fold 256 partials; finishB: 1 wave folds 24.

namespace {
constexpr int IMG   = 512;
constexpr int NCH   = 48;              // 16 * 3
constexpr int TW    = 32;              // tile cols
constexpr int TH    = 64;              // tile rows
constexpr int HALO  = 5;
constexpr int HROWS = TH + 2 * HALO;   // 74
constexpr int CSTR  = 34;              // hf_abcd col-pairs per row (32 + 2 pad) -> 272 B row, 16B aligned
constexpr int ESTR  = 40;              // hf_e halves per row -> 80 B, 16B aligned
constexpr int TPX   = IMG / TW;        // 16
constexpr int TPY   = IMG / TH;        // 8
constexpr int NBLK  = TPX * TPY * NCH; // 6144
constexpr int FB    = NBLK / 256;      // 24
}

__device__ inline __half2 pkrtz(float a, float b) {
    auto v = __builtin_amdgcn_cvt_pkrtz(a, b);   // v_cvt_pkrtz_f16_f32
    return *reinterpret_cast<__half2*>(&v);
}

__global__ __launch_bounds__(256) void ssim_tile_kernel(
    const float* __restrict__ pred, const float* __restrict__ tgt,
    float* __restrict__ partial)
{
    constexpr float Wf[11] = {
        0.00102838f, 0.00759876f, 0.03600077f, 0.10936069f, 0.21300554f,
        0.26601172f,
        0.21300554f, 0.10936069f, 0.03600077f, 0.00759876f, 0.00102838f };

    // broadcast weights and (W[d], W[d-1]) pair table (fold to constants)
    __half2 W2[11], WP[12];
    #pragma unroll
    for (int k = 0; k < 11; ++k) W2[k] = __float2half2_rn(Wf[k]);
    #pragma unroll
    for (int d = 0; d < 12; ++d) {
        float lo = (d <= 10) ? Wf[d] : 0.f;
        float hi = (d >= 1) ? Wf[d - 1] : 0.f;
        WP[d] = __floats2half2_rn(lo, hi);
    }

    __shared__ __align__(16) __half2 hf_abcd[HROWS][CSTR][2]; // 19.66 KB
    __shared__ __align__(16) __half  hf_e [HROWS][ESTR];      //  5.78 KB
    __shared__ float wred[4];

    const int t    = threadIdx.x;
    const int bid  = blockIdx.x;
    const int img  = bid >> 7;             // 128 tiles per plane
    const int tile = bid & 127;
    // XCD swizzle: horizontal neighbors (big halo overlap) are +-8 in bid
    const int txi  = tile >> 3;            // 0..15
    const int tyi  = tile & 7;             // 0..7
    const int tx   = txi * TW;
    const int ty   = tyi * TH;
    const bool xedge = (txi == 0) || (txi == TPX - 1);

    const float* __restrict__ p = pred + (size_t)img * (IMG * IMG);
    const float* __restrict__ q = tgt  + (size_t)img * (IMG * IMG);

    // ---- P2: horizontal conv, 74 rows x 4 col-groups of 8, global -> LDS ----
    for (int item = t; item < HROWS * 4; item += 256) {
        const int row  = item >> 2;            // 0..73
        const int g    = item & 3;
        const int gy   = ty + row - HALO;
        const int col8 = tx + (g << 3);        // multiple of 8
        const int lc   = g << 3;               // local col base
        const bool row_ok = (unsigned)gy < (unsigned)IMG;

        float4* dst_ab = (float4*)&hf_abcd[row][lc][0];
        float4* dst_e  = (float4*)&hf_e[row][lc];

        if (!row_ok) {
            float4 z4 = make_float4(0.f, 0.f, 0.f, 0.f);
            dst_ab[0] = z4; dst_ab[1] = z4; dst_ab[2] = z4; dst_ab[3] = z4;
            *dst_e = z4;
            continue;
        }

        const float* rp = p + gy * IMG;
        const float* rq = q + gy * IMG;

        float xf[24], yf[24];                  // cols col8-8 .. col8+15
        if (!xedge) {
            #pragma unroll
            for (int u = 0; u < 6; ++u) {
                *(float4*)&xf[4 * u] = *(const float4*)(rp + col8 - 8 + 4 * u);
                *(float4*)&yf[4 * u] = *(const float4*)(rq + col8 - 8 + 4 * u);
            }
        } else {
            #pragma unroll
            for (int i = 0; i < 24; ++i) {
                int gx = col8 - 8 + i;
                bool ok = (unsigned)gx < (unsigned)IMG;
                xf[i] = ok ? rp[gx] : 0.f;
                yf[i] = ok ? rq[gx] : 0.f;
            }
        }

        // inputs i=0..17 correspond to cols col8-5 .. col8+12 (= xf[i+3])
        __half2 hxy[18], hsq[18], hxe[18];
        #pragma unroll
        for (int i = 0; i < 18; ++i) {
            __half2 h = pkrtz(xf[i + 3], yf[i + 3]);      // (x, y)
            hxy[i] = h;
            hsq[i] = __hmul2(h, h);                       // (x2, y2)
            hxe[i] = __hmul2(h, __lowhigh2highlow(h));    // (xy, xy)
        }

        __half2 z = __float2half2_rn(0.f);
        __half2 aab[8] = {z,z,z,z,z,z,z,z};
        __half2 acd[8] = {z,z,z,z,z,z,z,z};
        __align__(16) __half2 ae[4] = {z,z,z,z};
        #pragma unroll
        for (int j = 0; j < 8; ++j)
            #pragma unroll
            for (int k = 0; k < 11; ++k) {
                aab[j] = __hfma2(W2[k], hxy[j + k], aab[j]);
                acd[j] = __hfma2(W2[k], hsq[j + k], acd[j]);
            }
        #pragma unroll
        for (int pp = 0; pp < 4; ++pp)
            #pragma unroll
            for (int d = 0; d < 12; ++d)
                ae[pp] = __hfma2(WP[d], hxe[2 * pp + d], ae[pp]);

        __align__(16) __half2 pairbuf[16];
        #pragma unroll
        for (int j = 0; j < 8; ++j) {
            pairbuf[2 * j]     = aab[j];
            pairbuf[2 * j + 1] = acd[j];
        }
        #pragma unroll
        for (int u = 0; u < 4; ++u)
            dst_ab[u] = ((const float4*)pairbuf)[u];
        *dst_e = *(const float4*)ae;           // 8 halves = 16 B
    }
    __syncthreads();

    // ---- P3: vertical conv; thread = (col c, 8-row group) ----
    const int c  = t & 31;
    const int r0 = (t >> 5) << 3;              // 0..56
    __half2 z = __float2half2_rn(0.f);
    __half2 bab[8] = {z,z,z,z,z,z,z,z};
    __half2 bcd[8] = {z,z,z,z,z,z,z,z};
    __half2 be[4]  = {z,z,z,z};
    #pragma unroll
    for (int i = 0; i < 18; ++i) {
        float2 v = *(const float2*)&hf_abcd[r0 + i][c][0];   // b64
        __half2 vab = ((const __half2*)&v)[0];
        __half2 vcd = ((const __half2*)&v)[1];
        __half2 ve2 = __half2half2(hf_e[r0 + i][c]);
        #pragma unroll
        for (int j = 0; j < 8; ++j) {
            int k = i - j;
            if (k >= 0 && k < 11) {
                bab[j] = __hfma2(W2[k], vab, bab[j]);
                bcd[j] = __hfma2(W2[k], vcd, bcd[j]);
            }
        }
        #pragma unroll
        for (int qq = 0; qq < 4; ++qq) {       // output row pairs (2qq, 2qq+1)
            int d = i - 2 * qq;
            if (d >= 0 && d < 12) be[qq] = __hfma2(WP[d], ve2, be[qq]);
        }
    }

    constexpr float C1 = 1e-4f, C2 = 9e-4f;
    float lsum = 0.f;
    #pragma unroll
    for (int j = 0; j < 8; ++j) {
        float2 ab = __half22float2(bab[j]);
        float2 cd = __half22float2(bcd[j]);
        float exy = __half2float((j & 1) ? __high2half(be[j >> 1])
                                         : __low2half(be[j >> 1]));
        float mx = ab.x, my = ab.y;
        float mxs = mx * mx, mys = my * my, mxy = mx * my;
        float sgx  = cd.x - mxs;
        float sgy  = cd.y - mys;
        float sgxy = exy  - mxy;
        float num = (2.f * mxy + C1) * (2.f * sgxy + C2);
        float den = (mxs + mys + C1) * (sgx + sgy + C2);
        lsum += num * __builtin_amdgcn_rcpf(den);
    }

    #pragma unroll
    for (int off = 32; off > 0; off >>= 1)
        lsum += __shfl_down(lsum, off, 64);
    if ((t & 63) == 0) wred[t >> 6] = lsum;
    __syncthreads();
    if (t == 0) partial[bid] = wred[0] + wred[1] + wred[2] + wred[3];
}

__global__ __launch_bounds__(256) void ssim_finishA(float* __restrict__ partial)
{
    __shared__ float wred[4];
    const int t = threadIdx.x;
    float s = partial[blockIdx.x * 256 + t];
    #pragma unroll
    for (int off = 32; off > 0; off >>= 1)
        s += __shfl_down(s, off, 64);
    if ((t & 63) == 0) wred[t >> 6] = s;
    __syncthreads();
    if (t == 0) partial[blockIdx.x * 256] = wred[0] + wred[1] + wred[2] + wred[3];
}

__global__ __launch_bounds__(64) void ssim_finishB(
    const float* __restrict__ partial, float* __restrict__ out)
{
    const int t = threadIdx.x;
    float s = (t < FB) ? partial[t * 256] : 0.f;
    #pragma unroll
    for (int off = 32; off > 0; off >>= 1)
        s += __shfl_down(s, off, 64);
    if (t == 0)
        out[0] = 1.f - s * (1.f / (float)((long long)NCH * IMG * IMG));
}

extern "C" void kernel_launch(void* const* d_in, const int* in_sizes, int n_in,
                              void* d_out, int out_size, void* d_ws, size_t ws_size,
                              hipStream_t stream)
{
    const float* pred = (const float*)d_in[0];
    const float* tgt  = (const float*)d_in[1];
    float* out     = (float*)d_out;
    float* partial = (float*)d_ws;    // NBLK floats = 24 KB

    ssim_tile_kernel<<<NBLK, 256, 0, stream>>>(pred, tgt, partial);
    ssim_finishA<<<FB, 256, 0, stream>>>(partial);
    ssim_finishB<<<1, 64, 0, stream>>>(partial, out);
}

// Round 8
// 138.950 us; speedup vs baseline: 2.2365x; 1.0246x over previous
//
#include <hip/hip_runtime.h>

// SSIM loss via MFMA band-matrix convolutions (gfx950).
// Both separable-conv passes are matmuls against constant band matrices:
//   H-pass: D(16x16) = A(rows x 32-col window, f16 from global) x Bband(32x16)
//           Bband[k][n] = W[k-n-3]; 5 fields share the A loads (x,y,x2,y2,xy).
//           D stored transposed to LDS hf_t[field][col][row] (b64/lane).
//   V-pass: D(16x16) = Aband(16x32) x B(hf_t frag, b128/lane)
//           Aband[m][k] = W[k-m]; f32 accum -> SSIM epilogue -> reduce.
// Per block: 64 rows x 32 cols of one (n,c) plane; 4 waves; LDS 28.2 KB.

namespace {
constexpr int IMG   = 512;
constexpr int NCH   = 48;              // 16 * 3
constexpr int TW    = 32;              // tile cols
constexpr int TH    = 64;              // tile rows
constexpr int RSTR  = 88;              // hf_t row-dim stride (f16 units)
constexpr int TPX   = IMG / TW;        // 16
constexpr int TPY   = IMG / TH;        // 8
constexpr int NBLK  = TPX * TPY * NCH; // 6144
constexpr int FB    = NBLK / 256;      // 24

constexpr float Wf[11] = {
    0.00102838f, 0.00759876f, 0.03600077f, 0.10936069f, 0.21300554f,
    0.26601172f,
    0.21300554f, 0.10936069f, 0.03600077f, 0.00759876f, 0.00102838f };
}

typedef _Float16 half8 __attribute__((ext_vector_type(8)));
typedef _Float16 half4v __attribute__((ext_vector_type(4)));
typedef _Float16 h2 __attribute__((ext_vector_type(2)));
typedef float float4v __attribute__((ext_vector_type(4)));

__device__ inline float band_w(int d) {   // W[d] for d in [0,11), else 0; select chain
    float v = 0.f;
    #pragma unroll
    for (int k = 0; k < 11; ++k) v = (d == k) ? Wf[k] : v;
    return v;
}

__device__ inline h2 pk(float a, float b) {
    auto v = __builtin_amdgcn_cvt_pkrtz(a, b);   // __fp16 x2; bit-identical to h2
    h2 r;
    __builtin_memcpy(&r, &v, sizeof(r));
    return r;
}

union H8 { half8 v; h2 p[4]; };

__global__ __launch_bounds__(256, 5) void ssim_tile_kernel(
    const float* __restrict__ pred, const float* __restrict__ tgt,
    float* __restrict__ partial)
{
    __shared__ __align__(16) _Float16 hf_t[5][TW][RSTR];   // 28.16 KB
    __shared__ float wred[4];

    const int t    = threadIdx.x;
    const int w    = t >> 6;              // wave 0..3
    const int lane = t & 63;
    const int nr   = lane & 15;           // m (A rows / D cols) or n (B cols)
    const int quad = lane >> 4;           // 0..3

    const int bid  = blockIdx.x;
    const int img  = bid >> 7;            // 128 tiles per plane
    const int tile = bid & 127;
    const int txi  = tile >> 3;           // XCD swizzle: horiz neighbors +-8 bid
    const int tyi  = tile & 7;
    const int tx   = txi * TW;
    const int ty   = tyi * TH;

    const float* __restrict__ p = pred + (size_t)img * (IMG * IMG);
    const float* __restrict__ q = tgt  + (size_t)img * (IMG * IMG);

    // ---- constant band fragments (built once; select chains fold early) ----
    half8 Aband, Bband;        // Aband[jj]=W[k-m] (vertical A), Bband[jj]=W[k-n-3] (horizontal B)
    #pragma unroll
    for (int jj = 0; jj < 8; ++jj) {
        int k = quad * 8 + jj;
        Aband[jj] = (_Float16)band_w(k - nr);
        Bband[jj] = (_Float16)band_w(k - nr - 3);
    }
    const float4v zf = {0.f, 0.f, 0.f, 0.f};
    const half8 z8 = {};

    // ================= P2: horizontal conv via MFMA, global -> hf_t =========
    for (int T = w; T < 10; T += 4) {
        const int s = T >> 1;             // HF row stripe 0..4
        const int j = T & 1;              // col tile 0..1
        const int gy  = ty + 16 * s + nr - 5;
        const int gyc = min(max(gy, 0), IMG - 1);
        const int cb  = tx + 16 * j - 8 + (quad << 3);     // frag col base (mult of 8)
        const int cbc = min(max(cb, 0), IMG - 8);
        const bool ok = ((unsigned)gy < (unsigned)IMG) &&
                        ((unsigned)cb <= (unsigned)(IMG - 8));
        const float* rp = p + gyc * IMG + cbc;
        const float* rq = q + gyc * IMG + cbc;
        float4 xa = *(const float4*)rp;
        float4 xb = *(const float4*)(rp + 4);
        float4 ya = *(const float4*)rq;
        float4 yb = *(const float4*)(rq + 4);

        H8 ax, ay;
        ax.p[0] = pk(xa.x, xa.y); ax.p[1] = pk(xa.z, xa.w);
        ax.p[2] = pk(xb.x, xb.y); ax.p[3] = pk(xb.z, xb.w);
        ay.p[0] = pk(ya.x, ya.y); ay.p[1] = pk(ya.z, ya.w);
        ay.p[2] = pk(yb.x, yb.y); ay.p[3] = pk(yb.z, yb.w);
        if (!ok) { ax.v = z8; ay.v = z8; }

        half8 fx  = ax.v;
        half8 fy  = ay.v;
        half8 fxx = fx * fx;
        half8 fyy = fy * fy;
        half8 fxy = fx * fy;

        float4v D[5];
        D[0] = __builtin_amdgcn_mfma_f32_16x16x32_f16(fx,  Bband, zf, 0, 0, 0);
        D[1] = __builtin_amdgcn_mfma_f32_16x16x32_f16(fy,  Bband, zf, 0, 0, 0);
        D[2] = __builtin_amdgcn_mfma_f32_16x16x32_f16(fxx, Bband, zf, 0, 0, 0);
        D[3] = __builtin_amdgcn_mfma_f32_16x16x32_f16(fyy, Bband, zf, 0, 0, 0);
        D[4] = __builtin_amdgcn_mfma_f32_16x16x32_f16(fxy, Bband, zf, 0, 0, 0);

        // D layout: col = nr (lane&15), rows = quad*4 + reg -> transposed b64 store
        const int col = 16 * j + nr;
        const int r0  = 16 * s + (quad << 2);
        #pragma unroll
        for (int f = 0; f < 5; ++f) {
            h2 lo = pk(D[f][0], D[f][1]);
            h2 hi = pk(D[f][2], D[f][3]);
            half4v hh = {lo[0], lo[1], hi[0], hi[1]};
            *(half4v*)&hf_t[f][col][r0] = hh;
        }
    }
    __syncthreads();

    // ================= P3: vertical conv via MFMA + SSIM epilogue ===========
    constexpr float C1 = 1e-4f, C2 = 9e-4f;
    float lsum = 0.f;
    for (int G = w; G < 8; G += 4) {
        const int s = G >> 1;             // out row stripe 0..3
        const int j = G & 1;
        const int col = 16 * j + nr;
        const int rb  = 16 * s + (quad << 3);
        float4v acc[5];
        #pragma unroll
        for (int f = 0; f < 5; ++f) {
            half8 bf = *(const half8*)&hf_t[f][col][rb];   // b128
            acc[f] = __builtin_amdgcn_mfma_f32_16x16x32_f16(Aband, bf, zf, 0, 0, 0);
        }
        #pragma unroll
        for (int r = 0; r < 4; ++r) {
            float mx = acc[0][r], my = acc[1][r];
            float ex2 = acc[2][r], ey2 = acc[3][r], exy = acc[4][r];
            float mxs = mx * mx, mys = my * my, mxy = mx * my;
            float sgx  = ex2 - mxs;
            float sgy  = ey2 - mys;
            float sgxy = exy - mxy;
            float num = (2.f * mxy + C1) * (2.f * sgxy + C2);
            float den = (mxs + mys + C1) * (sgx + sgy + C2);
            lsum += num * __builtin_amdgcn_rcpf(den);
        }
    }

    #pragma unroll
    for (int off = 32; off > 0; off >>= 1)
        lsum += __shfl_down(lsum, off, 64);
    if (lane == 0) wred[w] = lsum;
    __syncthreads();
    if (t == 0) partial[bid] = wred[0] + wred[1] + wred[2] + wred[3];
}

__global__ __launch_bounds__(256) void ssim_finishA(float* __restrict__ partial)
{
    __shared__ float wred[4];
    const int t = threadIdx.x;
    float s = partial[blockIdx.x * 256 + t];
    #pragma unroll
    for (int off = 32; off > 0; off >>= 1)
        s += __shfl_down(s, off, 64);
    if ((t & 63) == 0) wred[t >> 6] = s;
    __syncthreads();
    if (t == 0) partial[blockIdx.x * 256] = wred[0] + wred[1] + wred[2] + wred[3];
}

__global__ __launch_bounds__(64) void ssim_finishB(
    const float* __restrict__ partial, float* __restrict__ out)
{
    const int t = threadIdx.x;
    float s = (t < FB) ? partial[t * 256] : 0.f;
    #pragma unroll
    for (int off = 32; off > 0; off >>= 1)
        s += __shfl_down(s, off, 64);
    if (t == 0)
        out[0] = 1.f - s * (1.f / (float)((long long)NCH * IMG * IMG));
}

extern "C" void kernel_launch(void* const* d_in, const int* in_sizes, int n_in,
                              void* d_out, int out_size, void* d_ws, size_t ws_size,
                              hipStream_t stream)
{
    const float* pred = (const float*)d_in[0];
    const float* tgt  = (const float*)d_in[1];
    float* out     = (float*)d_out;
    float* partial = (float*)d_ws;    // NBLK floats = 24 KB

    ssim_tile_kernel<<<NBLK, 256, 0, stream>>>(pred, tgt, partial);
    ssim_finishA<<<FB, 256, 0, stream>>>(partial);
    ssim_finishB<<<1, 64, 0, stream>>>(partial, out);
}

// Round 9
// 138.297 us; speedup vs baseline: 2.2470x; 1.0047x over previous
//
#include <hip/hip_runtime.h>

// SSIM loss via MFMA band-matrix convolutions (gfx950).
//   H-pass: D(16x16) = A(16 rows x 32-col window, f16 from global) x Bband(32x16)
//           Bband[k][n] = W[k-n-3]; 5 fields share A loads (x,y,x2,y2,xy).
//           D stored transposed to LDS hf_t[field][col][hf_row] (b64/lane).
//   V-pass: D(16x16) = Aband(16x32) x B(hf_t frag, b128/lane)
//           Aband[m][k] = W[k-m]; f32 accum -> packed-f32 SSIM -> reduce.
// R9: 16x128 tile (no col-tile overlap, LDS 23.75 KB -> 6 blocks/CU),
//     v_pk_*_f32 epilogue, balanced P3 (2 groups/wave).

namespace {
constexpr int IMG   = 512;
constexpr int NCH   = 48;              // 16 * 3
constexpr int TW    = 16;              // tile cols
constexpr int TH    = 128;             // tile rows
constexpr int RSTR  = 152;             // hf_t row-dim stride (f16 units, mult of 8)
constexpr int TPX   = IMG / TW;        // 32
constexpr int TPY   = IMG / TH;        // 4
constexpr int NBLK  = TPX * TPY * NCH; // 6144
constexpr int FB    = NBLK / 256;      // 24

constexpr float Wf[11] = {
    0.00102838f, 0.00759876f, 0.03600077f, 0.10936069f, 0.21300554f,
    0.26601172f,
    0.21300554f, 0.10936069f, 0.03600077f, 0.00759876f, 0.00102838f };
}

typedef _Float16 half8 __attribute__((ext_vector_type(8)));
typedef _Float16 half4v __attribute__((ext_vector_type(4)));
typedef _Float16 h2 __attribute__((ext_vector_type(2)));
typedef float float4v __attribute__((ext_vector_type(4)));
typedef float float2v __attribute__((ext_vector_type(2)));

__device__ inline float band_w(int d) {   // W[d] for d in [0,11), else 0
    float v = 0.f;
    #pragma unroll
    for (int k = 0; k < 11; ++k) v = (d == k) ? Wf[k] : v;
    return v;
}

__device__ inline h2 pk(float a, float b) {
    auto v = __builtin_amdgcn_cvt_pkrtz(a, b);
    h2 r;
    __builtin_memcpy(&r, &v, sizeof(r));
    return r;
}

union H8 { half8 v; h2 p[4]; };

__global__ __launch_bounds__(256, 6) void ssim_tile_kernel(
    const float* __restrict__ pred, const float* __restrict__ tgt,
    float* __restrict__ partial)
{
    __shared__ __align__(16) _Float16 hf_t[5][TW][RSTR];   // 23.75 KB
    __shared__ float wred[4];

    const int t    = threadIdx.x;
    const int w    = t >> 6;              // wave 0..3
    const int lane = t & 63;
    const int nr   = lane & 15;
    const int quad = lane >> 4;

    const int bid  = blockIdx.x;
    const int img  = bid >> 7;            // 128 tiles per plane
    const int tile = bid & 127;
    const int txi  = tile >> 2;           // 0..31 (horiz neighbors +-4 bid)
    const int tyi  = tile & 3;            // 0..3
    const int tx   = txi * TW;
    const int ty   = tyi * TH;

    const float* __restrict__ p = pred + (size_t)img * (IMG * IMG);
    const float* __restrict__ q = tgt  + (size_t)img * (IMG * IMG);

    // ---- constant band fragments (select chains fold to immediates) ----
    half8 Aband, Bband;    // Aband[jj]=W[k-m] (V-pass A), Bband[jj]=W[k-n-3] (H-pass B)
    #pragma unroll
    for (int jj = 0; jj < 8; ++jj) {
        int k = quad * 8 + jj;
        Aband[jj] = (_Float16)band_w(k - nr);
        Bband[jj] = (_Float16)band_w(k - nr - 3);
    }
    const float4v zf = {0.f, 0.f, 0.f, 0.f};
    const half8 z8 = {};

    // ===== P2: horizontal conv via MFMA, global -> hf_t (9 stripes) =====
    for (int s = w; s < 9; s += 4) {
        const int gy  = ty + 16 * s + nr - 5;
        const int gyc = min(max(gy, 0), IMG - 1);
        const int cb  = tx - 8 + (quad << 3);      // frag col base (mult of 8)
        const int cbc = min(max(cb, 0), IMG - 8);
        const bool ok = ((unsigned)gy < (unsigned)IMG) &&
                        ((unsigned)cb <= (unsigned)(IMG - 8));
        const float* rp = p + gyc * IMG + cbc;
        const float* rq = q + gyc * IMG + cbc;
        float4 xa = *(const float4*)rp;
        float4 xb = *(const float4*)(rp + 4);
        float4 ya = *(const float4*)rq;
        float4 yb = *(const float4*)(rq + 4);

        H8 ax, ay;
        ax.p[0] = pk(xa.x, xa.y); ax.p[1] = pk(xa.z, xa.w);
        ax.p[2] = pk(xb.x, xb.y); ax.p[3] = pk(xb.z, xb.w);
        ay.p[0] = pk(ya.x, ya.y); ay.p[1] = pk(ya.z, ya.w);
        ay.p[2] = pk(yb.x, yb.y); ay.p[3] = pk(yb.z, yb.w);
        if (!ok) { ax.v = z8; ay.v = z8; }

        half8 fx  = ax.v;
        half8 fy  = ay.v;
        half8 fxx = fx * fx;
        half8 fyy = fy * fy;
        half8 fxy = fx * fy;

        float4v D[5];
        D[0] = __builtin_amdgcn_mfma_f32_16x16x32_f16(fx,  Bband, zf, 0, 0, 0);
        D[1] = __builtin_amdgcn_mfma_f32_16x16x32_f16(fy,  Bband, zf, 0, 0, 0);
        D[2] = __builtin_amdgcn_mfma_f32_16x16x32_f16(fxx, Bband, zf, 0, 0, 0);
        D[3] = __builtin_amdgcn_mfma_f32_16x16x32_f16(fyy, Bband, zf, 0, 0, 0);
        D[4] = __builtin_amdgcn_mfma_f32_16x16x32_f16(fxy, Bband, zf, 0, 0, 0);

        // D: col n = nr, rows m = quad*4+reg -> hf_t[f][n][16s+4q+reg] (b64)
        const int r0 = 16 * s + (quad << 2);
        #pragma unroll
        for (int f = 0; f < 5; ++f) {
            h2 lo = pk(D[f][0], D[f][1]);
            h2 hi = pk(D[f][2], D[f][3]);
            half4v hh = {lo[0], lo[1], hi[0], hi[1]};
            *(half4v*)&hf_t[f][nr][r0] = hh;
        }
    }
    __syncthreads();

    // ===== P3: vertical conv via MFMA + packed-f32 SSIM epilogue =====
    constexpr float C1 = 1e-4f, C2 = 9e-4f;
    const float2v C1v = {C1, C1};
    const float2v C2v = {C2, C2};
    const float2v K12 = {C1 + C2, C1 + C2};
    float2v lsum2 = {0.f, 0.f};
    for (int s = w; s < 8; s += 4) {
        const int rb = 16 * s + (quad << 3);
        float4v acc[5];
        #pragma unroll
        for (int f = 0; f < 5; ++f) {
            half8 bf = *(const half8*)&hf_t[f][nr][rb];   // b128
            acc[f] = __builtin_amdgcn_mfma_f32_16x16x32_f16(Aband, bf, zf, 0, 0, 0);
        }
        #pragma unroll
        for (int h = 0; h < 2; ++h) {
            float2v mx  = {acc[0][2*h], acc[0][2*h+1]};
            float2v my  = {acc[1][2*h], acc[1][2*h+1]};
            float2v ex2 = {acc[2][2*h], acc[2][2*h+1]};
            float2v ey2 = {acc[3][2*h], acc[3][2*h+1]};
            float2v exy = {acc[4][2*h], acc[4][2*h+1]};
            float2v P  = mx * my;
            float2v U  = mx * mx + my * my + C1v;     // mus^2 sum + C1
            float2v n1 = 2.f * P + C1v;
            float2v n2 = 2.f * (exy - P) + C2v;
            float2v num = n1 * n2;
            float2v e1 = (ex2 + ey2) - U + K12;       // sgx+sgy+C2
            float2v den = U * e1;
            float2v r = {__builtin_amdgcn_rcpf(den.x),
                         __builtin_amdgcn_rcpf(den.y)};
            lsum2 += num * r;
        }
    }
    float lsum = lsum2.x + lsum2.y;

    #pragma unroll
    for (int off = 32; off > 0; off >>= 1)
        lsum += __shfl_down(lsum, off, 64);
    if (lane == 0) wred[w] = lsum;
    __syncthreads();
    if (t == 0) partial[bid] = wred[0] + wred[1] + wred[2] + wred[3];
}

__global__ __launch_bounds__(256) void ssim_finishA(float* __restrict__ partial)
{
    __shared__ float wred[4];
    const int t = threadIdx.x;
    float s = partial[blockIdx.x * 256 + t];
    #pragma unroll
    for (int off = 32; off > 0; off >>= 1)
        s += __shfl_down(s, off, 64);
    if ((t & 63) == 0) wred[t >> 6] = s;
    __syncthreads();
    if (t == 0) partial[blockIdx.x * 256] = wred[0] + wred[1] + wred[2] + wred[3];
}

__global__ __launch_bounds__(64) void ssim_finishB(
    const float* __restrict__ partial, float* __restrict__ out)
{
    const int t = threadIdx.x;
    float s = (t < FB) ? partial[t * 256] : 0.f;
    #pragma unroll
    for (int off = 32; off > 0; off >>= 1)
        s += __shfl_down(s, off, 64);
    if (t == 0)
        out[0] = 1.f - s * (1.f / (float)((long long)NCH * IMG * IMG));
}

extern "C" void kernel_launch(void* const* d_in, const int* in_sizes, int n_in,
                              void* d_out, int out_size, void* d_ws, size_t ws_size,
                              hipStream_t stream)
{
    const float* pred = (const float*)d_in[0];
    const float* tgt  = (const float*)d_in[1];
    float* out     = (float*)d_out;
    float* partial = (float*)d_ws;    // NBLK floats = 24 KB

    ssim_tile_kernel<<<NBLK, 256, 0, stream>>>(pred, tgt, partial);
    ssim_finishA<<<FB, 256, 0, stream>>>(partial);
    ssim_finishB<<<1, 64, 0, stream>>>(partial, out);
}